// Round 1
// baseline (92.157 us; speedup 1.0000x reference)
//
#include <hip/hip_runtime.h>
#include <hip/hip_bf16.h>

#define K_DIM   1024
#define N_OUT   256
#define XY_COLS 2304   // 9*256

typedef __bf16 bf16x4 __attribute__((ext_vector_type(4)));
typedef __bf16 bf16x8 __attribute__((ext_vector_type(8)));
typedef float  f32x4  __attribute__((ext_vector_type(4)));

// K1: xy[256][2304] = input @ W^T + b_xy   (fp32 out to workspace)
// Tile BM=32, BN=64, BK=32. Grid 8*36=288 blocks, 256 threads (4 waves).
// Wave w: 16-row group (w>>1), 32-col group (w&1) -> two 16x16x32 MFMAs/step.
__global__ __launch_bounds__(256) void gemm_xy_kernel(
    const float* __restrict__ A,
    const float* __restrict__ W,
    const float* __restrict__ bias,
    float* __restrict__ xy)
{
    const int t   = threadIdx.x;
    const int bid = blockIdx.x;
    const int mt  = bid / 36;
    const int nt  = bid - mt * 36;
    const int m0  = mt * 32;
    const int n0  = nt * 64;

    __shared__ __align__(16) __bf16 sA[32][32];
    __shared__ __align__(16) __bf16 sB[64][32];

    // staging: A-tile 32x32 (4 fp32/thread), W-tile 64x32 (8 fp32/thread)
    const int ra = t >> 3;
    const int ka = (t & 7) * 4;
    const int rw = t >> 2;
    const int kw = (t & 3) * 8;

    const float* pA = A + (m0 + ra) * K_DIM + ka;
    const float* pW = W + (n0 + rw) * K_DIM + kw;

    const int lane = t & 63;
    const int wv   = t >> 6;
    const int mh   = wv >> 1;
    const int nh   = wv & 1;
    const int l15  = lane & 15;
    const int quad = lane >> 4;

    f32x4 acc0 = {0.f, 0.f, 0.f, 0.f};
    f32x4 acc1 = {0.f, 0.f, 0.f, 0.f};

    float4 ar  = *(const float4*)pA;
    float4 wr0 = *(const float4*)pW;
    float4 wr1 = *(const float4*)(pW + 4);

    #pragma unroll 1
    for (int kk = 0; kk < K_DIM / 32; ++kk) {
        if (kk) __syncthreads();
        bf16x4 av = { (__bf16)ar.x, (__bf16)ar.y, (__bf16)ar.z, (__bf16)ar.w };
        *(bf16x4*)&sA[ra][ka] = av;
        bf16x8 wvec = { (__bf16)wr0.x, (__bf16)wr0.y, (__bf16)wr0.z, (__bf16)wr0.w,
                        (__bf16)wr1.x, (__bf16)wr1.y, (__bf16)wr1.z, (__bf16)wr1.w };
        *(bf16x8*)&sB[rw][kw] = wvec;
        if (kk + 1 < K_DIM / 32) {   // prefetch next K-slab into registers
            pA += 32; pW += 32;
            ar  = *(const float4*)pA;
            wr0 = *(const float4*)pW;
            wr1 = *(const float4*)(pW + 4);
        }
        __syncthreads();
        // A-frag: A[m=lane&15][k=quad*8+j]; B-frag: Wt row n=lane&15, same k
        bf16x8 af  = *(bf16x8*)&sA[16 * mh + l15][quad * 8];
        bf16x8 bf0 = *(bf16x8*)&sB[32 * nh + l15][quad * 8];
        bf16x8 bf1 = *(bf16x8*)&sB[32 * nh + 16 + l15][quad * 8];
        acc0 = __builtin_amdgcn_mfma_f32_16x16x32_bf16(af, bf0, acc0, 0, 0, 0);
        acc1 = __builtin_amdgcn_mfma_f32_16x16x32_bf16(af, bf1, acc1, 0, 0, 0);
    }

    // C/D layout: col = lane&15, row = quad*4 + reg
    const int row0 = m0 + 16 * mh + quad * 4;
    const int col0 = n0 + 32 * nh + l15;
    const float b0 = bias[col0];
    const float b1 = bias[col0 + 16];
    #pragma unroll
    for (int r = 0; r < 4; ++r) {
        xy[(row0 + r) * XY_COLS + col0]      = acc0[r] + b0;
        xy[(row0 + r) * XY_COLS + col0 + 16] = acc1[r] + b1;
    }
}

// K2: per batch b: S[c][j] = sum_i exp(x_c[i]) * exp(y_c[i^j])
//     out[b][j] = sum_c w_out[c]*log(S[c][j]) + w_out[4]*skip[j] + b_out
// Grid 256 blocks, 512 threads (8 waves). Wave wv -> copy c=wv>>1, i-half h=wv&1.
// Lane jh handles j = 4*jh + jl (jl=0..3). i^j = 4*(ih^jh) + (l^jl):
// one b128 ey gather feeds 16 FMAs; ex read is wave-uniform broadcast.
__global__ __launch_bounds__(512) void softxor_kernel(
    const float* __restrict__ xy,
    const float* __restrict__ w_out,
    const float* __restrict__ b_out,
    float* __restrict__ out)
{
    const int b = blockIdx.x;
    const int t = threadIdx.x;

    __shared__ __align__(16) float ex[4][N_OUT];
    __shared__ __align__(16) float ey[4][N_OUT];
    __shared__ __align__(16) float sk[N_OUT];
    __shared__ __align__(16) float part[8][N_OUT];

    const float* row = xy + (long)b * XY_COLS;

    // load the 2304-col row; exp() the first 2048 (x,y), raw skip
    for (int e4 = t; e4 < XY_COLS / 4; e4 += 512) {
        float4 v = *(const float4*)(row + e4 * 4);
        int e = e4 * 4;
        if (e < 1024) {
            float* d = &ex[e >> 8][e & 255];
            d[0] = __expf(v.x); d[1] = __expf(v.y); d[2] = __expf(v.z); d[3] = __expf(v.w);
        } else if (e < 2048) {
            float* d = &ey[(e >> 8) - 4][e & 255];
            d[0] = __expf(v.x); d[1] = __expf(v.y); d[2] = __expf(v.z); d[3] = __expf(v.w);
        } else {
            float* d = &sk[e - 2048];
            d[0] = v.x; d[1] = v.y; d[2] = v.z; d[3] = v.w;
        }
    }
    __syncthreads();

    const int wv = t >> 6;
    const int c  = wv >> 1;
    const int h  = wv & 1;
    const int jh = t & 63;

    float S0 = 0.f, S1 = 0.f, S2 = 0.f, S3 = 0.f;
    const int ih0 = h * 32;
    #pragma unroll 4
    for (int ih = ih0; ih < ih0 + 32; ++ih) {
        float4 xa = *(const float4*)&ex[c][ih * 4];            // broadcast
        float4 yb = *(const float4*)&ey[c][(ih ^ jh) * 4];     // permuted gather
        S0 += xa.x * yb.x + xa.y * yb.y + xa.z * yb.z + xa.w * yb.w;  // jl=0
        S1 += xa.x * yb.y + xa.y * yb.x + xa.z * yb.w + xa.w * yb.z;  // jl=1
        S2 += xa.x * yb.z + xa.y * yb.w + xa.z * yb.x + xa.w * yb.y;  // jl=2
        S3 += xa.x * yb.w + xa.y * yb.z + xa.z * yb.y + xa.w * yb.x;  // jl=3
    }
    *(float4*)&part[wv][jh * 4] = make_float4(S0, S1, S2, S3);
    __syncthreads();

    if (t < N_OUT) {
        float acc = w_out[4] * sk[t] + b_out[0];
        #pragma unroll
        for (int cc = 0; cc < 4; ++cc) {
            float S = part[2 * cc][t] + part[2 * cc + 1][t];
            acc += w_out[cc] * __logf(S);
        }
        out[b * N_OUT + t] = acc;
    }
}

extern "C" void kernel_launch(void* const* d_in, const int* in_sizes, int n_in,
                              void* d_out, int out_size, void* d_ws, size_t ws_size,
                              hipStream_t stream) {
    const float* input = (const float*)d_in[0];
    const float* W_xy  = (const float*)d_in[1];
    const float* b_xy  = (const float*)d_in[2];
    const float* w_out = (const float*)d_in[3];
    const float* b_out = (const float*)d_in[4];
    float* outp = (float*)d_out;
    float* xy   = (float*)d_ws;   // 256*2304*4 = 2.36 MB

    gemm_xy_kernel<<<288, 256, 0, stream>>>(input, W_xy, b_xy, xy);
    softxor_kernel<<<256, 512, 0, stream>>>(xy, w_out, b_out, outp);
}